// Round 11
// baseline (14859.845 us; speedup 1.0000x reference)
//
#include <hip/hip_runtime.h>

#define BDIM 256   // batch
#define SDIM 512   // seq len
#define HDIM 512   // hidden
#define VDIM 128   // vocab
#define NBG 16     // batch groups
#define BB 16      // batch per group
#define NHS 16     // hidden slices (blocks per bg)
#define HHU 32     // hidden units per block (16 per gate wave)
#define WIHP 136   // padded pitch for W_ih slice
#define TRP 20     // transpose scratch pitch (ushorts; 40B rows -> 8B-aligned u64 reads)
#define NT 192     // 3 waves: 2 gate waves + 1 proj wave
// Static LDS: 34816 (2 Wih halves) + 1280 (2 transpose pads) + PAD = 83200 B.
// 2x83200 > 163840 => exactly 1 block/CU: co-residency of all 256 blocks, REQUIRED
// by the flag protocol (proven R0..R9; dynamic-LDS pad is not honored, R4).
#define PAD_LDS 47104

typedef unsigned short ushort_t;
typedef unsigned long long u64_t;
typedef __attribute__((ext_vector_type(8))) short bf16x8;
typedef __attribute__((ext_vector_type(4))) float f32x4;
typedef union { u64_t d[2]; bf16x8 v; } cvt_t;

__device__ __forceinline__ ushort_t f2bf(float x) {
  unsigned u = __builtin_bit_cast(unsigned, x);
  u += 0x7fffu + ((u >> 16) & 1u);
  return (ushort_t)(u >> 16);
}
__device__ __forceinline__ float bf2f(ushort_t b) {
  unsigned u = ((unsigned)b) << 16;
  return __builtin_bit_cast(float, u);
}
__device__ __forceinline__ float sigmoidf_(float x) { return 1.f / (1.f + __expf(-x)); }
__device__ __forceinline__ float tanhf_(float x) { return 2.f / (1.f + __expf(-2.f * x)) - 1.f; }

__device__ __forceinline__ void pack_store8(ushort_t* dst, const float* s) {
  ushort_t tmp[8];
#pragma unroll
  for (int j = 0; j < 8; ++j) tmp[j] = f2bf(s[j]);
  uint4 v;
  v.x = (unsigned)tmp[0] | ((unsigned)tmp[1] << 16);
  v.y = (unsigned)tmp[2] | ((unsigned)tmp[3] << 16);
  v.z = (unsigned)tmp[4] | ((unsigned)tmp[5] << 16);
  v.w = (unsigned)tmp[6] | ((unsigned)tmp[7] << 16);
  *(uint4*)dst = v;
}

// 8 consecutive f32 -> bf16x8 fragment (same f2bf rounding as pack_store8)
__device__ __forceinline__ bf16x8 ldw8(const float* p) {
  const float4 a = *(const float4*)p;
  const float4 b = *(const float4*)(p + 4);
  bf16x8 r;
  r[0] = (short)f2bf(a.x); r[1] = (short)f2bf(a.y);
  r[2] = (short)f2bf(a.z); r[3] = (short)f2bf(a.w);
  r[4] = (short)f2bf(b.x); r[5] = (short)f2bf(b.y);
  r[6] = (short)f2bf(b.z); r[7] = (short)f2bf(b.w);
  return r;
}

// Sync protocol: R8/R9-proven primitives ONLY (relaxed agent atomics via the LLC;
// wave-local s_waitcnt vmcnt(0) drain before relaxed swap-publish; NO acquire/
// release [R7: 2x], NO sc0 [R1-R5], NO data polling [R6]).
// NEW structure: ZERO __syncthreads in the step loop. Each wave is autonomous:
//  - gate wave (w=0,1): holds ALL 4 gates' W_hh frags in regs (256 VGPR; 1 wave/
//    SIMD at launch_bounds(192,1) -> 512 budget). Loads h(t) fragments DIRECTLY
//    from LLC to regs (no LDS staging/barrier), 4 MFMA chains, in-lane c/h update
//    (i,f,g,o land in the same lane), wave-local LDS transpose (lgkmcnt only),
//    u64 swap stores, vmcnt drain, own flag. 48 flags/bg = 16 blocks x 3 waves.
//  - proj wave (w=2): decoupled consumer; polls flags, loads h(t) itself, writes
//    logits, publishes its own flag (guards h buffer reuse).
__global__ void __launch_bounds__(NT, 1) lstm_kernel(
    const int* __restrict__ C_idx, const int* __restrict__ E,
    const float* __restrict__ eWih, const float* __restrict__ eWhh,
    const float* __restrict__ ebi, const float* __restrict__ ebh,
    const float* __restrict__ dWih, const float* __restrict__ dWhh,
    const float* __restrict__ dbi, const float* __restrict__ dbh,
    const float* __restrict__ pW, const float* __restrict__ pb,
    unsigned* flags, ushort_t* hbuf, ushort_t* logits) {
  __shared__ ushort_t Wih0_s[64 * WIHP];  // wave0-private gather table
  __shared__ ushort_t Wih1_s[64 * WIHP];  // wave1-private gather table
  __shared__ ushort_t tr_s[2][16 * TRP];  // per-gate-wave transpose scratch
  __shared__ char pad_s[PAD_LDS];         // forces 1 block/CU

  const int tid = threadIdx.x;
  const int w = tid >> 6;
  const int lane = tid & 63;
  const int bg = blockIdx.x & 15;
  const int hs = blockIdx.x >> 4;
  const int u = lane & 15, q = lane >> 4;

  if (tid == 0) *(volatile char*)pad_s = 0;  // keep pad allocated

  if (w < 2) {
    // ================= gate wave: 16 units (ub..ub+15), all 4 gates =================
    ushort_t* myWih = w ? Wih1_s : Wih0_s;
    ushort_t* mytr = tr_s[w];
    const int ub = hs * HHU + w * 16;  // global unit base

    bf16x8 wfi[16], wff[16], wfg[16], wfo[16];
    float bs0, bs1, bs2, bs3;
    float creg[4] = {0.f, 0.f, 0.f, 0.f};

#pragma unroll
    for (int kt = 0; kt < 16; ++kt) {
      wfi[kt] = ldw8(eWhh + (size_t)(0 * HDIM + ub + u) * HDIM + kt * 32 + q * 8);
      wff[kt] = ldw8(eWhh + (size_t)(1 * HDIM + ub + u) * HDIM + kt * 32 + q * 8);
      wfg[kt] = ldw8(eWhh + (size_t)(2 * HDIM + ub + u) * HDIM + kt * 32 + q * 8);
      wfo[kt] = ldw8(eWhh + (size_t)(3 * HDIM + ub + u) * HDIM + kt * 32 + q * 8);
    }
    bs0 = ebi[0 * HDIM + ub + u] + ebh[0 * HDIM + ub + u];
    bs1 = ebi[1 * HDIM + ub + u] + ebh[1 * HDIM + ub + u];
    bs2 = ebi[2 * HDIM + ub + u] + ebh[2 * HDIM + ub + u];
    bs3 = ebi[3 * HDIM + ub + u] + ebh[3 * HDIM + ub + u];
    for (int c = lane; c < 64 * 16; c += 64) {  // my 64-row Wih half (g*16+unit)
      int r = c >> 4, k8 = (c & 15) * 8;
      int gr = (r >> 4) * HDIM + ub + (r & 15);
      pack_store8(&myWih[r * WIHP + k8], eWih + (size_t)gr * VDIM + k8);
    }
    asm volatile("s_waitcnt lgkmcnt(0)" ::: "memory");  // table visible to own wave

    for (int t = 0; t < 1024; ++t) {
      if (t == 512) {  // wave-private phase switch (own table, own regs: no hazard)
#pragma unroll
        for (int kt = 0; kt < 16; ++kt) {
          wfi[kt] = ldw8(dWhh + (size_t)(0 * HDIM + ub + u) * HDIM + kt * 32 + q * 8);
          wff[kt] = ldw8(dWhh + (size_t)(1 * HDIM + ub + u) * HDIM + kt * 32 + q * 8);
          wfg[kt] = ldw8(dWhh + (size_t)(2 * HDIM + ub + u) * HDIM + kt * 32 + q * 8);
          wfo[kt] = ldw8(dWhh + (size_t)(3 * HDIM + ub + u) * HDIM + kt * 32 + q * 8);
        }
        bs0 = dbi[0 * HDIM + ub + u] + dbh[0 * HDIM + ub + u];
        bs1 = dbi[1 * HDIM + ub + u] + dbh[1 * HDIM + ub + u];
        bs2 = dbi[2 * HDIM + ub + u] + dbh[2 * HDIM + ub + u];
        bs3 = dbi[3 * HDIM + ub + u] + dbh[3 * HDIM + ub + u];
        for (int c = lane; c < 64 * 16; c += 64) {
          int r = c >> 4, k8 = (c & 15) * 8;
          int gr = (r >> 4) * HDIM + ub + (r & 15);
          pack_store8(&myWih[r * WIHP + k8], dWih + (size_t)gr * VDIM + k8);
        }
        asm volatile("s_waitcnt lgkmcnt(0)" ::: "memory");
      }
      // wait: everyone (48 waves of this bg) finished step t-1 => h(t) visible AND
      // buf[(t+1)&1]'s old content h(t-1) is no longer being read anywhere.
      if (t > 0 && lane < 48) {
        const unsigned* fp = &flags[bg * 48 + lane];
        int spins = 0;
        while (__hip_atomic_load(fp, __ATOMIC_RELAXED, __HIP_MEMORY_SCOPE_AGENT) <
               (unsigned)t) {
          __builtin_amdgcn_s_sleep(1);
          if (++spins > (1 << 20)) break;  // bailout (never hit when co-resident)
        }
      }
      // input indices for my 4 batches (read-only inputs: plain cached loads)
      int ix[4];
#pragma unroll
      for (int r = 0; r < 4; ++r) {
        const int b = bg * BB + q * 4 + r;
        ix[r] = (t >= 512) ? E[(size_t)b * (SDIM + 1) + (t - 512)]
                           : C_idx[(size_t)b * SDIM + t];
      }
      // acc init = bias + one-hot gather (identical arithmetic to R9)
      f32x4 ai, av, ag, ao;
#pragma unroll
      for (int r = 0; r < 4; ++r) {
        ai[r] = bs0 + bf2f(myWih[(0 * 16 + u) * WIHP + ix[r]]);
        av[r] = bs1 + bf2f(myWih[(1 * 16 + u) * WIHP + ix[r]]);
        ag[r] = bs2 + bf2f(myWih[(2 * 16 + u) * WIHP + ix[r]]);
        ao[r] = bs3 + bf2f(myWih[(3 * 16 + u) * WIHP + ix[r]]);
      }
      // h(t) A-fragments straight from LLC (relaxed agent u64 loads, R8/R9-proven);
      // load latency overlaps the 4 MFMA chains.
      const u64_t* src = (const u64_t*)hbuf +
                         ((size_t)(t & 1) * BDIM + bg * BB + u) * (HDIM / 4) + q * 2;
#pragma unroll
      for (int kt = 0; kt < 16; ++kt) {
        cvt_t cv;
        cv.d[0] = __hip_atomic_load(src + kt * 8, __ATOMIC_RELAXED, __HIP_MEMORY_SCOPE_AGENT);
        cv.d[1] = __hip_atomic_load(src + kt * 8 + 1, __ATOMIC_RELAXED, __HIP_MEMORY_SCOPE_AGENT);
        ai = __builtin_amdgcn_mfma_f32_16x16x32_bf16(cv.v, wfi[kt], ai, 0, 0, 0);
        av = __builtin_amdgcn_mfma_f32_16x16x32_bf16(cv.v, wff[kt], av, 0, 0, 0);
        ag = __builtin_amdgcn_mfma_f32_16x16x32_bf16(cv.v, wfg[kt], ag, 0, 0, 0);
        ao = __builtin_amdgcn_mfma_f32_16x16x32_bf16(cv.v, wfo[kt], ao, 0, 0, 0);
      }
      // in-lane LSTM update (c in registers), write h bf16 to wave-local scratch
#pragma unroll
      for (int r = 0; r < 4; ++r) {
        float cn = sigmoidf_(av[r]) * creg[r] + sigmoidf_(ai[r]) * tanhf_(ag[r]);
        creg[r] = cn;
        mytr[(q * 4 + r) * TRP + u] = f2bf(sigmoidf_(ao[r]) * tanhf_(cn));
      }
      asm volatile("s_waitcnt lgkmcnt(0)" ::: "memory");  // wave-sync transpose
      {
        const int b2 = lane & 15, grp = lane >> 4;  // 16 batches x 4 unit-groups
        u64_t pk = *(const u64_t*)&mytr[b2 * TRP + grp * 4];
        u64_t* dst = (u64_t*)hbuf +
                     ((size_t)((t + 1) & 1) * BDIM + bg * BB + b2) * (HDIM / 4) +
                     (ub >> 2) + grp;
        (void)__hip_atomic_exchange(dst, pk, __ATOMIC_RELAXED, __HIP_MEMORY_SCOPE_AGENT);
      }
      asm volatile("s_waitcnt vmcnt(0)" ::: "memory");  // wave-local drain (R8-proven)
      if (lane == 0)
        (void)__hip_atomic_exchange(&flags[bg * 48 + hs * 3 + w], (unsigned)(t + 1),
                                    __ATOMIC_RELAXED, __HIP_MEMORY_SCOPE_AGENT);
    }
  } else {
    // ================= proj wave: logits rows hs*8 .. hs*8+7 =================
    bf16x8 wf[16];
#pragma unroll
    for (int kt = 0; kt < 16; ++kt)
      wf[kt] = ldw8(pW + (size_t)(hs * 8 + (u & 7)) * HDIM + kt * 32 + q * 8);
    const float pbv = (u < 8) ? pb[hs * 8 + u] : 0.f;
    // steps 0..512 read nothing: declare them done up front (monotonic flag)
    if (lane == 0)
      (void)__hip_atomic_exchange(&flags[bg * 48 + hs * 3 + 2], 513u,
                                  __ATOMIC_RELAXED, __HIP_MEMORY_SCOPE_AGENT);
    for (int t = 513; t <= 1024; ++t) {
      if (lane < 48) {
        const unsigned* fp = &flags[bg * 48 + lane];
        int spins = 0;
        while (__hip_atomic_load(fp, __ATOMIC_RELAXED, __HIP_MEMORY_SCOPE_AGENT) <
               (unsigned)t) {
          __builtin_amdgcn_s_sleep(1);
          if (++spins > (1 << 20)) break;
        }
      }
      f32x4 acc = {0.f, 0.f, 0.f, 0.f};
      const u64_t* src = (const u64_t*)hbuf +
                         ((size_t)(t & 1) * BDIM + bg * BB + u) * (HDIM / 4) + q * 2;
#pragma unroll
      for (int kt = 0; kt < 16; ++kt) {
        cvt_t cv;
        cv.d[0] = __hip_atomic_load(src + kt * 8, __ATOMIC_RELAXED, __HIP_MEMORY_SCOPE_AGENT);
        cv.d[1] = __hip_atomic_load(src + kt * 8 + 1, __ATOMIC_RELAXED, __HIP_MEMORY_SCOPE_AGENT);
        acc = __builtin_amdgcn_mfma_f32_16x16x32_bf16(cv.v, wf[kt], acc, 0, 0, 0);
      }
      if (u < 8) {
        const int ld = t - 513;  // logits step 0..511
#pragma unroll
        for (int r = 0; r < 4; ++r)
          logits[((size_t)ld * BDIM + bg * BB + q * 4 + r) * VDIM + hs * 8 + u] =
              f2bf(acc[r] + pbv);
      }
      asm volatile("s_waitcnt vmcnt(0)" ::: "memory");  // h reads of step t retired
      if (lane == 0)
        (void)__hip_atomic_exchange(&flags[bg * 48 + hs * 3 + 2], (unsigned)(t + 1),
                                    __ATOMIC_RELAXED, __HIP_MEMORY_SCOPE_AGENT);
    }
  }
}

__global__ void loss_kernel(const ushort_t* __restrict__ logits, const int* __restrict__ E,
                            float* __restrict__ partial) {
  const int t = blockIdx.x;   // 512
  const int b = threadIdx.x;  // 256
  const ushort_t* row = logits + ((size_t)t * BDIM + b) * VDIM;
  float mx = -3.0e38f;
  for (int k = 0; k < VDIM; ++k) mx = fmaxf(mx, bf2f(row[k]));
  float se = 0.f;
  for (int k = 0; k < VDIM; ++k) se += __expf(bf2f(row[k]) - mx);
  const int tgt = E[(size_t)b * (SDIM + 1) + t];
  float nll = (mx + __logf(se)) - bf2f(row[tgt]);
  float m = (tgt != 0) ? 1.f : 0.f;
  __shared__ float s1[BDIM];
  __shared__ float s0[BDIM];
  s1[b] = nll * m;
  s0[b] = m;
  __syncthreads();
  for (int s = 128; s > 0; s >>= 1) {
    if (b < s) {
      s1[b] += s1[b + s];
      s0[b] += s0[b + s];
    }
    __syncthreads();
  }
  if (b == 0) partial[t] = (s0[0] > 0.f) ? s1[0] / s0[0] : 0.f;
}

__global__ void reduce_kernel(const float* __restrict__ partial, float* __restrict__ out) {
  __shared__ float sm[SDIM];
  sm[threadIdx.x] = partial[threadIdx.x];
  __syncthreads();
  for (int s = 256; s > 0; s >>= 1) {
    if (threadIdx.x < s) sm[threadIdx.x] += sm[threadIdx.x + s];
    __syncthreads();
  }
  if (threadIdx.x == 0) out[0] = sm[0];
}

extern "C" void kernel_launch(void* const* d_in, const int* in_sizes, int n_in,
                              void* d_out, int out_size, void* d_ws, size_t ws_size,
                              hipStream_t stream) {
  const int* C_idx = (const int*)d_in[0];
  const int* E = (const int*)d_in[1];
  const float* eWih = (const float*)d_in[2];
  const float* eWhh = (const float*)d_in[3];
  const float* ebi = (const float*)d_in[4];
  const float* ebh = (const float*)d_in[5];
  const float* dWih = (const float*)d_in[6];
  const float* dWhh = (const float*)d_in[7];
  const float* dbi = (const float*)d_in[8];
  const float* dbh = (const float*)d_in[9];
  const float* pW = (const float*)d_in[10];
  const float* pb = (const float*)d_in[11];

  char* ws = (char*)d_ws;
  unsigned* flags = (unsigned*)ws;                             // 16*48*4 B (pad to 32768)
  ushort_t* hbuf = (ushort_t*)(ws + 32768);                    // 2*256*512*2   = 524288 B
  ushort_t* logits = (ushort_t*)(ws + 32768 + 524288);         // 512*256*128*2 = 32 MiB
  float* partial = (float*)(ws + 32768 + 524288 + 33554432);   // 512*4 B

  // zero flags + h double-buffer (h0 = c0 = 0); ws is poisoned 0xAA each call
  hipMemsetAsync(d_ws, 0, 32768 + 524288, stream);
  lstm_kernel<<<256, NT, 0, stream>>>(C_idx, E, eWih, eWhh, ebi, ebh, dWih, dWhh,
                                      dbi, dbh, pW, pb, flags, hbuf, logits);
  loss_kernel<<<512, 256, 0, stream>>>(logits, E, partial);
  reduce_kernel<<<1, 512, 0, stream>>>(partial, (float*)d_out);
}

// Round 12
// 3554.396 us; speedup vs baseline: 4.1807x; 4.1807x over previous
//
#include <hip/hip_runtime.h>

#define BDIM 256   // batch
#define SDIM 512   // seq len
#define HDIM 512   // hidden
#define VDIM 128   // vocab
#define NBG 16     // batch groups
#define BB 16      // batch per group
#define NHS 16     // hidden slices (blocks per bg)
#define HHU 32     // hidden units per block
#define KP 520     // padded LDS pitch for K=512 (bf16 elems)
#define WIHP 136   // padded pitch for W_ih slice
#define GP 33      // padded pitch for g_s/c_s (32 units + 1)
#define NT 320     // threads per block (5 waves)
// Static LDS: 62624 + PAD = 83104 B; 2x83104 > 163840 => exactly 1 block/CU.
// Co-residency of all 256 blocks is REQUIRED by the flag protocol (proven R0..R9;
// dynamic-LDS launch bytes are NOT honored by the harness — R4 evidence).
#define PAD_LDS 20480

typedef unsigned short ushort_t;
typedef unsigned long long u64_t;
typedef __attribute__((ext_vector_type(8))) short bf16x8;
typedef __attribute__((ext_vector_type(4))) float f32x4;

__device__ __forceinline__ ushort_t f2bf(float x) {
  unsigned u = __builtin_bit_cast(unsigned, x);
  u += 0x7fffu + ((u >> 16) & 1u);
  return (ushort_t)(u >> 16);
}
__device__ __forceinline__ float bf2f(ushort_t b) {
  unsigned u = ((unsigned)b) << 16;
  return __builtin_bit_cast(float, u);
}
__device__ __forceinline__ float sigmoidf_(float x) { return 1.f / (1.f + __expf(-x)); }
__device__ __forceinline__ float tanhf_(float x) { return 2.f / (1.f + __expf(-2.f * x)) - 1.f; }

__device__ __forceinline__ void pack_store8(ushort_t* dst, const float* s) {
  ushort_t tmp[8];
#pragma unroll
  for (int j = 0; j < 8; ++j) tmp[j] = f2bf(s[j]);
  uint4 v;
  v.x = (unsigned)tmp[0] | ((unsigned)tmp[1] << 16);
  v.y = (unsigned)tmp[2] | ((unsigned)tmp[3] << 16);
  v.z = (unsigned)tmp[4] | ((unsigned)tmp[5] << 16);
  v.w = (unsigned)tmp[6] | ((unsigned)tmp[7] << 16);
  *(uint4*)dst = v;
}

// 8 consecutive f32 -> bf16x8 fragment (same f2bf rounding as pack_store8)
__device__ __forceinline__ bf16x8 ldw8(const float* p) {
  const float4 a = *(const float4*)p;
  const float4 b = *(const float4*)(p + 4);
  bf16x8 r;
  r[0] = (short)f2bf(a.x); r[1] = (short)f2bf(a.y);
  r[2] = (short)f2bf(a.z); r[3] = (short)f2bf(a.w);
  r[4] = (short)f2bf(b.x); r[5] = (short)f2bf(b.y);
  r[6] = (short)f2bf(b.z); r[7] = (short)f2bf(b.w);
  return r;
}

// W_ih slice (one-hot gather table, 128 rows = 4 gates x 32 units) + fused bias.
__device__ __forceinline__ void load_wih(ushort_t* Wih_s, float* bias_s, const float* Wih,
                                         const float* bi, const float* bh, int hs, int tid) {
  for (int c = tid; c < 128 * 16; c += NT) {  // 128 rows x 128 cols, 8-float chunks
    int r = c >> 4, k8 = (c & 15) * 8;
    int gr = (r >> 5) * HDIM + hs * HHU + (r & 31);
    pack_store8(&Wih_s[r * WIHP + k8], Wih + (size_t)gr * VDIM + k8);
  }
  if (tid < 128) {
    int gr = (tid >> 5) * HDIM + hs * HHU + (tid & 31);
    bias_s[tid] = bi[gr] + bh[gr];
  }
}

// Gate wave w (0..3): B-fragments of W_hh gate-w rows for unit-tile T (T*16+u) in
// registers. Lane(u,q): fragment kt covers k = kt*32 + q*8 .. +8 (R4-proven layout).
__device__ __forceinline__ void load_whh_frag(bf16x8* wf, const float* Whh,
                                              int gate, int hs, int tile, int u, int q) {
  const size_t r = ((size_t)gate * HDIM + hs * HHU + tile * 16 + u) * HDIM;
#pragma unroll
  for (int kt = 0; kt < 16; ++kt) wf[kt] = ldw8(Whh + r + kt * 32 + q * 8);
}

// Sync protocol: R8/R9-proven primitives (relaxed agent atomics via the LLC;
// wave-local s_waitcnt vmcnt(0) drain before relaxed swap publish; NO acquire/
// release [R7: 2x], NO sc0 [R1-R5], NO data polling [R6], NO per-lane scattered
// atomics [R11: 4x]).
// R12 change vs R9 (wave re-roling for overlap — the only diff):
//   poll -> wave 2, idx prefetch -> wave 3. Between BAR-B(t) and BAR-P(t+1):
//   w0/w1's update+drain+publish runs CONCURRENTLY with w2's poll and w3's idx
//   load, so BAR-P releases at max(drain, poll) instead of their sum.
__global__ void __launch_bounds__(NT) lstm_kernel(
    const int* __restrict__ C_idx, const int* __restrict__ E,
    const float* __restrict__ eWih, const float* __restrict__ eWhh,
    const float* __restrict__ ebi, const float* __restrict__ ebh,
    const float* __restrict__ dWih, const float* __restrict__ dWhh,
    const float* __restrict__ dbi, const float* __restrict__ dbh,
    const float* __restrict__ pW, const float* __restrict__ pb,
    unsigned* flags, ushort_t* hbuf, ushort_t* logits) {
  __shared__ ushort_t Wih_s[128 * WIHP];
  __shared__ ushort_t h_s[16 * KP];
  __shared__ float g_s[4 * BB * GP];
  __shared__ float c_s[BB * GP];
  __shared__ float bias_s[128];
  __shared__ float pb_s[8];
  __shared__ int idx_s[BB];
  __shared__ char pad_s[PAD_LDS];  // forces 1 block/CU (see #define)

  const int tid = threadIdx.x;
  const int w = tid >> 6;
  const int lane = tid & 63;
  const int bg = blockIdx.x & 15;
  const int hs = blockIdx.x >> 4;
  const int u = lane & 15, q = lane >> 4;

  if (tid == 0) *(volatile char*)pad_s = 0;  // keep pad allocated

  load_wih(Wih_s, bias_s, eWih, ebi, ebh, hs, tid);
  for (int i = tid; i < BB * GP; i += NT) c_s[i] = 0.f;

  // B-fragments in registers. Gate waves 0..3: two unit-tiles of gate w (128 VGPR).
  // Proj wave 4: its 8 pW rows in wf0 (rows 8..15 duplicate row u&7, outputs unused);
  // pW never changes -> loaded once.
  bf16x8 wf0[16], wf1[16];
  if (w < 4) {
    load_whh_frag(wf0, eWhh, w, hs, 0, u, q);
    load_whh_frag(wf1, eWhh, w, hs, 1, u, q);
  } else {
    const size_t pr = (size_t)(hs * 8 + (u & 7)) * HDIM;
#pragma unroll
    for (int kt = 0; kt < 16; ++kt) wf0[kt] = ldw8(pW + pr + kt * 32 + q * 8);
  }
  if (tid < 8) pb_s[tid] = pb[hs * 8 + tid];
  __syncthreads();

  for (int t = 0; t <= 1024; ++t) {
    const bool last = (t == 1024);
    if (t == 512) {  // phase switch: decoder weights (all old-table reads ended at
                     // BAR-B of t=511; writes complete before BAR-P below)
      load_wih(Wih_s, bias_s, dWih, dbi, dbh, hs, tid);
      if (w < 4) {
        load_whh_frag(wf0, dWhh, w, hs, 0, u, q);
        load_whh_frag(wf1, dWhh, w, hs, 1, u, q);
      }
    }
    // idx prefetch on wave 3 (overlaps w0/w1's update+drain of step t-1)
    if (!last && w == 3 && lane < BB) {
      idx_s[lane] = (t >= 512) ? E[(size_t)(bg * BB + lane) * (SDIM + 1) + (t - 512)]
                               : C_idx[(size_t)(bg * BB + lane) * SDIM + t];
    }
    // Poll on wave 2 (overlaps w0/w1's update+drain of step t-1): wait for all 32
    // producer-waves (16 blocks x 2 waves) of this bg to have finished step t-1.
    if (t > 0 && w == 2 && lane < 32) {
      const unsigned* fp = &flags[bg * 32 + lane];
      int spins = 0;
      while (__hip_atomic_load(fp, __ATOMIC_RELAXED, __HIP_MEMORY_SCOPE_AGENT) <
             (unsigned)t) {
        __builtin_amdgcn_s_sleep(1);
        if (++spins > (1 << 20)) break;  // deadlock bailout (never hit if co-resident)
      }
    }
    __syncthreads();  // BAR-P: h(t) visible; idx_s/Wih_s writes complete

    // stage h[16,512] bf16 (16 KB) -> LDS via LLC-coherent coalesced 8B loads
    {
      const u64_t* src = (const u64_t*)(hbuf + ((size_t)(t & 1) * BDIM + bg * BB) * HDIM);
      u64_t tmp[7];
#pragma unroll
      for (int k = 0; k < 7; ++k) {
        int c = tid + k * NT;
        if (c < 2048)
          tmp[k] = __hip_atomic_load(src + c, __ATOMIC_RELAXED, __HIP_MEMORY_SCOPE_AGENT);
      }
#pragma unroll
      for (int k = 0; k < 7; ++k) {
        int c = tid + k * NT;
        if (c < 2048) {
          int r = c >> 7, k4 = (c & 127) * 4;
          *(u64_t*)&h_s[r * KP + k4] = tmp[k];
        }
      }
    }
    __syncthreads();  // BAR-A: h_s ready

    const bool proj_on = (t >= 513);
    if ((w < 4 && !last) || (w == 4 && proj_on)) {
      f32x4 acc0 = {0.f, 0.f, 0.f, 0.f};  // unit-tile 0 (units u)      x batches q*4+r
      f32x4 acc1 = {0.f, 0.f, 0.f, 0.f};  // unit-tile 1 (units 16+u)   x batches q*4+r
      if (w < 4) {
        // acc init = bias + one-hot gather from W_ih (row = gate*32 + unit)
        const float bv0 = bias_s[w * 32 + u], bv1 = bias_s[w * 32 + 16 + u];
        const int ro0 = (w * 32 + u) * WIHP, ro1 = (w * 32 + 16 + u) * WIHP;
#pragma unroll
        for (int r = 0; r < 4; ++r) {
          const int ix = idx_s[q * 4 + r];
          acc0[r] = bv0 + bf2f(Wih_s[ro0 + ix]);
          acc1[r] = bv1 + bf2f(Wih_s[ro1 + ix]);
        }
      }
      const ushort_t* ap = &h_s[u * KP + q * 8];  // batch rows 0..15
#pragma unroll
      for (int kt = 0; kt < 16; ++kt) {
        bf16x8 af = *(const bf16x8*)(ap + kt * 32);
        acc0 = __builtin_amdgcn_mfma_f32_16x16x32_bf16(af, wf0[kt], acc0, 0, 0, 0);
        if (w < 4) acc1 = __builtin_amdgcn_mfma_f32_16x16x32_bf16(af, wf1[kt], acc1, 0, 0, 0);
      }
      if (w < 4) {
#pragma unroll
        for (int r = 0; r < 4; ++r) {
          g_s[(w * BB + q * 4 + r) * GP + u] = acc0[r];
          g_s[(w * BB + q * 4 + r) * GP + 16 + u] = acc1[r];
        }
      } else if (u < 8) {
        const int ld = t - 513;  // logits step index 0..511
        const float pbv = pb_s[u];
#pragma unroll
        for (int r = 0; r < 4; ++r) {
          logits[((size_t)ld * BDIM + bg * BB + q * 4 + r) * VDIM + hs * 8 + u] =
              f2bf(acc0[r] + pbv);
        }
      }
    }
    __syncthreads();  // BAR-B: g_s ready; all h_s/idx_s/Wih_s reads of step t done

    if (!last) {
      if (tid < 128) {  // c/h update: 16 batches x 32 units, 4 units/thread (w0+w1)
        const int b = tid >> 3, uq = tid & 7;
        ushort_t hv[4];
#pragma unroll
        for (int j = 0; j < 4; ++j) {
          const int uu = uq * 4 + j;
          float ig = g_s[(0 * BB + b) * GP + uu];
          float fg = g_s[(1 * BB + b) * GP + uu];
          float gg = g_s[(2 * BB + b) * GP + uu];
          float og = g_s[(3 * BB + b) * GP + uu];
          float co = c_s[b * GP + uu];
          float cn = sigmoidf_(fg) * co + sigmoidf_(ig) * tanhf_(gg);
          c_s[b * GP + uu] = cn;
          hv[j] = f2bf(sigmoidf_(og) * tanhf_(cn));
        }
        u64_t pk = (u64_t)hv[0] | ((u64_t)hv[1] << 16) | ((u64_t)hv[2] << 32) |
                   ((u64_t)hv[3] << 48);
        u64_t* dst = (u64_t*)(hbuf + ((size_t)((t + 1) & 1) * BDIM + bg * BB + b) * HDIM +
                              hs * HHU + uq * 4);
        // fire-and-forget swap: executes at the LLC, vmcnt ack (R9-proven)
        (void)__hip_atomic_exchange(dst, pk, __ATOMIC_RELAXED, __HIP_MEMORY_SCOPE_AGENT);
      }
      // Per-wave ordered publish: drain THIS wave's h swaps (wave-local vmcnt, no
      // cache-wide fence), then relaxed flag swap. Runs concurrently with the NEXT
      // iteration's poll (w2) and idx load (w3).
      if (w < 2) {
        asm volatile("s_waitcnt vmcnt(0)" ::: "memory");
        if (lane == 0)
          (void)__hip_atomic_exchange(&flags[bg * 32 + hs * 2 + w], (unsigned)(t + 1),
                                      __ATOMIC_RELAXED, __HIP_MEMORY_SCOPE_AGENT);
      }
    }
  }
}

__global__ void loss_kernel(const ushort_t* __restrict__ logits, const int* __restrict__ E,
                            float* __restrict__ partial) {
  const int t = blockIdx.x;   // 512
  const int b = threadIdx.x;  // 256
  const ushort_t* row = logits + ((size_t)t * BDIM + b) * VDIM;
  float mx = -3.0e38f;
  for (int k = 0; k < VDIM; ++k) mx = fmaxf(mx, bf2f(row[k]));
  float se = 0.f;
  for (int k = 0; k < VDIM; ++k) se += __expf(bf2f(row[k]) - mx);
  const int tgt = E[(size_t)b * (SDIM + 1) + t];
  float nll = (mx + __logf(se)) - bf2f(row[tgt]);
  float m = (tgt != 0) ? 1.f : 0.f;
  __shared__ float s1[BDIM];
  __shared__ float s0[BDIM];
  s1[b] = nll * m;
  s0[b] = m;
  __syncthreads();
  for (int s = 128; s > 0; s >>= 1) {
    if (b < s) {
      s1[b] += s1[b + s];
      s0[b] += s0[b + s];
    }
    __syncthreads();
  }
  if (b == 0) partial[t] = (s0[0] > 0.f) ? s1[0] / s0[0] : 0.f;
}

__global__ void reduce_kernel(const float* __restrict__ partial, float* __restrict__ out) {
  __shared__ float sm[SDIM];
  sm[threadIdx.x] = partial[threadIdx.x];
  __syncthreads();
  for (int s = 256; s > 0; s >>= 1) {
    if (threadIdx.x < s) sm[threadIdx.x] += sm[threadIdx.x + s];
    __syncthreads();
  }
  if (threadIdx.x == 0) out[0] = sm[0];
}

extern "C" void kernel_launch(void* const* d_in, const int* in_sizes, int n_in,
                              void* d_out, int out_size, void* d_ws, size_t ws_size,
                              hipStream_t stream) {
  const int* C_idx = (const int*)d_in[0];
  const int* E = (const int*)d_in[1];
  const float* eWih = (const float*)d_in[2];
  const float* eWhh = (const float*)d_in[3];
  const float* ebi = (const float*)d_in[4];
  const float* ebh = (const float*)d_in[5];
  const float* dWih = (const float*)d_in[6];
  const float* dWhh = (const float*)d_in[7];
  const float* dbi = (const float*)d_in[8];
  const float* dbh = (const float*)d_in[9];
  const float* pW = (const float*)d_in[10];
  const float* pb = (const float*)d_in[11];

  char* ws = (char*)d_ws;
  unsigned* flags = (unsigned*)ws;                             // 16*32*4 B (pad to 32768)
  ushort_t* hbuf = (ushort_t*)(ws + 32768);                    // 2*256*512*2   = 524288 B
  ushort_t* logits = (ushort_t*)(ws + 32768 + 524288);         // 512*256*128*2 = 32 MiB
  float* partial = (float*)(ws + 32768 + 524288 + 33554432);   // 512*4 B

  // zero flags + h double-buffer (h0 = c0 = 0); ws is poisoned 0xAA each call
  hipMemsetAsync(d_ws, 0, 32768 + 524288, stream);
  lstm_kernel<<<256, NT, 0, stream>>>(C_idx, E, eWih, eWhh, ebi, ebh, dWih, dWhh,
                                      dbi, dbh, pW, pb, flags, hbuf, logits);
  loss_kernel<<<512, 256, 0, stream>>>(logits, E, partial);
  reduce_kernel<<<1, 512, 0, stream>>>(partial, (float*)d_out);
}